// Round 9
// baseline (224.992 us; speedup 1.0000x reference)
//
#include <hip/hip_runtime.h>
#include <stdint.h>

#define N_NODES 50000
#define N_EDGES 800000
#define IN_DIM  128
#define HID_DIM 64
#define OUT_DIM 64

#define NPB     256                         // partition blocks
#define EPB     (N_EDGES / NPB)             // 3125 edges per block (exact)
#define BSH     9                           // bucket shift: 512 nodes/bucket
#define NB      ((N_NODES + 511) >> BSH)    // 98 buckets

// ---------------------------------------------------------------------------
// bf16 helpers (RNE pack, bit-shift unpack; accumulate in fp32)
// ---------------------------------------------------------------------------
__device__ __forceinline__ uint32_t f2bf(float f) {
    uint32_t u = __float_as_uint(f);
    return (u + 0x7FFFu + ((u >> 16) & 1u)) >> 16;
}
__device__ __forceinline__ uint32_t pack2bf(float a, float b) {
    return f2bf(a) | (f2bf(b) << 16);
}
__device__ __forceinline__ float bflo(uint32_t v) { return __uint_as_float(v << 16); }
__device__ __forceinline__ float bfhi(uint32_t v) { return __uint_as_float(v & 0xFFFF0000u); }

// ---------------------------------------------------------------------------
// k_bhist: per-(block,bucket) histogram of dst. histT[bkt*NPB + blk].
// ---------------------------------------------------------------------------
__global__ __launch_bounds__(256) void k_bhist(const int* __restrict__ ei,
                                               int* __restrict__ histT) {
    __shared__ int hist[NB];
    const int blk = blockIdx.x, tid = threadIdx.x;
    if (tid < NB) hist[tid] = 0;
    __syncthreads();
    const int e0 = blk * EPB;
    for (int e = e0 + tid; e < e0 + EPB; e += 256)
        atomicAdd(&hist[ei[N_EDGES + e] >> BSH], 1);
    __syncthreads();
    if (tid < NB) histT[tid * NPB + blk] = hist[tid];
}

// ---------------------------------------------------------------------------
// k_bscan: single-block exclusive scan (in place) of histT[NB*NPB] in
// bucket-major order; emits bucketstart[NB+1].
// ---------------------------------------------------------------------------
__global__ __launch_bounds__(256) void k_bscan(int* __restrict__ histT,
                                               int* __restrict__ bucketstart) {
    const int t = threadIdx.x;
    const int CH = (NB * NPB) / 256;        // 98 contiguous elements per thread
    const int base = t * CH;
    int s = 0;
#pragma unroll 7
    for (int i = 0; i < CH; ++i) s += histT[base + i];

    int wid = t >> 6, lane = t & 63;
    int incl = s;
    for (int o = 1; o < 64; o <<= 1) {
        int v = __shfl_up(incl, o, 64);
        if (lane >= o) incl += v;
    }
    __shared__ int wt[4];
    if (lane == 63) wt[wid] = incl;
    __syncthreads();
    int woff = 0;
    for (int w = 0; w < wid; ++w) woff += wt[w];
    int excl = woff + incl - s;

#pragma unroll 7
    for (int i = 0; i < CH; ++i) {
        int v = histT[base + i];
        histT[base + i] = excl;
        excl += v;
    }
    __syncthreads();
    if (t < NB) bucketstart[t] = histT[t * NPB];
    if (t == 0) bucketstart[NB] = N_EDGES;
}

// ---------------------------------------------------------------------------
// k_part: re-stream edges; write rec = src | dlo<<16 into this block's
// reserved contiguous chunk of each bucket (coalesced-ish, XCD-friendly).
// ---------------------------------------------------------------------------
__global__ __launch_bounds__(256) void k_part(const int* __restrict__ ei,
                                              const int* __restrict__ histT,
                                              int* __restrict__ brec) {
    __shared__ int cursor[NB];
    const int blk = blockIdx.x, tid = threadIdx.x;
    if (tid < NB) cursor[tid] = histT[tid * NPB + blk];
    __syncthreads();
    const int e0 = blk * EPB;
    for (int e = e0 + tid; e < e0 + EPB; e += 256) {
        int s = ei[e];
        int d = ei[N_EDGES + e];
        int b = d >> BSH;
        int pos = atomicAdd(&cursor[b], 1);
        brec[pos] = s | ((d & 511) << 16);
    }
}

// ---------------------------------------------------------------------------
// k_csr: one block per bucket (512 nodes).  Counts per-node deg in LDS,
// block-scans to per-node offsets, emits rowstart & dinv (coalesced), then
// scatters final edata (src only) — whole CSR region written by ONE wg/XCD.
// ---------------------------------------------------------------------------
__global__ __launch_bounds__(256) void k_csr(const int* __restrict__ brec,
                                             const int* __restrict__ bucketstart,
                                             int* __restrict__ rowstart,
                                             float* __restrict__ dinv,
                                             int* __restrict__ edata) {
    __shared__ int deg[512];
    __shared__ int segoff[512];
    __shared__ int wt[4];
    const int b = blockIdx.x, tid = threadIdx.x;
    const int lo = b << BSH;
    const int cstart = bucketstart[b];
    const int cend   = bucketstart[b + 1];

    deg[tid] = 0;
    deg[tid + 256] = 0;
    __syncthreads();

    for (int j = cstart + tid; j < cend; j += 256)
        atomicAdd(&deg[brec[j] >> 16], 1);
    __syncthreads();

    const int i0 = tid << 1;
    const int d0 = deg[i0], d1 = deg[i0 + 1];
    const int s = d0 + d1;
    int wid = tid >> 6, lane = tid & 63;
    int incl = s;
    for (int o = 1; o < 64; o <<= 1) {
        int v = __shfl_up(incl, o, 64);
        if (lane >= o) incl += v;
    }
    if (lane == 63) wt[wid] = incl;
    __syncthreads();
    int woff = 0;
    for (int w = 0; w < wid; ++w) woff += wt[w];
    const int excl = woff + incl - s;

    segoff[i0]     = excl;
    segoff[i0 + 1] = excl + d0;

    if (lo + i0 < N_NODES) {
        rowstart[lo + i0] = cstart + excl;
        dinv[lo + i0] = rsqrtf((float)d0 + 1.0f);
    }
    if (lo + i0 + 1 < N_NODES) {
        rowstart[lo + i0 + 1] = cstart + excl + d0;
        dinv[lo + i0 + 1] = rsqrtf((float)d1 + 1.0f);
    }
    if (b == NB - 1 && tid == 0) rowstart[N_NODES] = cend;
    __syncthreads();

    for (int j = cstart + tid; j < cend; j += 256) {
        int rec = brec[j];
        int pos = cstart + atomicAdd(&segoff[rec >> 16], 1);
        edata[pos] = rec & 0xFFFF;
    }
}

// ---------------------------------------------------------------------------
// k_gemm3: HSB[n,64] (bf16) = (X[n,K] @ W[K,64]) * dinv[row].
// ---------------------------------------------------------------------------
__device__ __forceinline__ void fma4(float4& acc, const float4& xv,
                                     const float4& w0, const float4& w1,
                                     const float4& w2, const float4& w3) {
    acc.x += xv.x * w0.x + xv.y * w1.x + xv.z * w2.x + xv.w * w3.x;
    acc.y += xv.x * w0.y + xv.y * w1.y + xv.z * w2.y + xv.w * w3.y;
    acc.z += xv.x * w0.z + xv.y * w1.z + xv.z * w2.z + xv.w * w3.z;
    acc.w += xv.x * w0.w + xv.y * w1.w + xv.z * w2.w + xv.w * w3.w;
}

__device__ __forceinline__ uint2 packbf4(const float4& a, float s) {
    return make_uint2(pack2bf(a.x * s, a.y * s), pack2bf(a.z * s, a.w * s));
}

template <int K>
__global__ __launch_bounds__(256) void k_gemm3(const float* __restrict__ X,
                                               const float* __restrict__ W,
                                               const float* __restrict__ dinv,
                                               uint32_t* __restrict__ HSB, int n) {
    constexpr int QK = K / 4;
    __shared__ float4 Ws[K * 16];
    const int tid = threadIdx.x;
    const int row0 = blockIdx.x * 64;

    for (int f = tid; f < K * 16; f += 256) Ws[f] = ((const float4*)W)[f];
    __syncthreads();

    const int c4 = tid & 15;
    const int r0 = row0 + ((tid >> 4) << 2);
    const float4* Xq = (const float4*)X;

    float4 a0 = make_float4(0.f, 0.f, 0.f, 0.f);
    float4 a1 = a0, a2 = a0, a3 = a0;

    if (r0 + 3 < n) {
        const float4* xp0 = Xq + (size_t)r0 * QK;
        const float4* xp1 = xp0 + QK;
        const float4* xp2 = xp1 + QK;
        const float4* xp3 = xp2 + QK;
#pragma unroll 4
        for (int k4 = 0; k4 < QK; ++k4) {
            const float4 x0 = xp0[k4];
            const float4 x1 = xp1[k4];
            const float4 x2 = xp2[k4];
            const float4 x3 = xp3[k4];
            const float4 w0 = Ws[(k4 * 4 + 0) * 16 + c4];
            const float4 w1 = Ws[(k4 * 4 + 1) * 16 + c4];
            const float4 w2 = Ws[(k4 * 4 + 2) * 16 + c4];
            const float4 w3 = Ws[(k4 * 4 + 3) * 16 + c4];
            fma4(a0, x0, w0, w1, w2, w3);
            fma4(a1, x1, w0, w1, w2, w3);
            fma4(a2, x2, w0, w1, w2, w3);
            fma4(a3, x3, w0, w1, w2, w3);
        }
        const float4 dv = ((const float4*)dinv)[r0 >> 2];
        ((uint2*)HSB)[((size_t)(r0 + 0) * 32 + c4 * 2) >> 1] = packbf4(a0, dv.x);
        ((uint2*)HSB)[((size_t)(r0 + 1) * 32 + c4 * 2) >> 1] = packbf4(a1, dv.y);
        ((uint2*)HSB)[((size_t)(r0 + 2) * 32 + c4 * 2) >> 1] = packbf4(a2, dv.z);
        ((uint2*)HSB)[((size_t)(r0 + 3) * 32 + c4 * 2) >> 1] = packbf4(a3, dv.w);
    } else {
        const float4 z = make_float4(0.f, 0.f, 0.f, 0.f);
        for (int k4 = 0; k4 < QK; ++k4) {
            const float4 x0 = (r0 + 0 < n) ? Xq[(size_t)(r0 + 0) * QK + k4] : z;
            const float4 x1 = (r0 + 1 < n) ? Xq[(size_t)(r0 + 1) * QK + k4] : z;
            const float4 x2 = (r0 + 2 < n) ? Xq[(size_t)(r0 + 2) * QK + k4] : z;
            const float4 x3 = (r0 + 3 < n) ? Xq[(size_t)(r0 + 3) * QK + k4] : z;
            const float4 w0 = Ws[(k4 * 4 + 0) * 16 + c4];
            const float4 w1 = Ws[(k4 * 4 + 1) * 16 + c4];
            const float4 w2 = Ws[(k4 * 4 + 2) * 16 + c4];
            const float4 w3 = Ws[(k4 * 4 + 3) * 16 + c4];
            fma4(a0, x0, w0, w1, w2, w3);
            fma4(a1, x1, w0, w1, w2, w3);
            fma4(a2, x2, w0, w1, w2, w3);
            fma4(a3, x3, w0, w1, w2, w3);
        }
        if (r0 + 0 < n) ((uint2*)HSB)[((size_t)(r0 + 0) * 32 + c4 * 2) >> 1] = packbf4(a0, dinv[r0 + 0]);
        if (r0 + 1 < n) ((uint2*)HSB)[((size_t)(r0 + 1) * 32 + c4 * 2) >> 1] = packbf4(a1, dinv[r0 + 1]);
        if (r0 + 2 < n) ((uint2*)HSB)[((size_t)(r0 + 2) * 32 + c4 * 2) >> 1] = packbf4(a2, dinv[r0 + 2]);
        if (r0 + 3 < n) ((uint2*)HSB)[((size_t)(r0 + 3) * 32 + c4 * 2) >> 1] = packbf4(a3, dinv[r0 + 3]);
    }
}

// ---------------------------------------------------------------------------
// k_gw2: FUSED gather-1 + ReLU + GEMM-2.
// Per node (8 lanes x 8 dims): r = relu(dinv*(sum hs1[j] + hs1[i]) + b1) in
// regs; then hs2 = (r @ W2)*dinv packed bf16.  W2 staged in LDS with
// bank-permuted rows: row k at slot (k&7)*8 + (k>>3), stride 68 floats ->
// the 8 lane-groups (k = lane*8+kk) read 8 distinct bank quads (4*lane),
// conflict-free b128 reads.  8-lane shfl_xor allreduce, static indexing only.
// ---------------------------------------------------------------------------
__global__ __launch_bounds__(256) void k_gw2(const int* __restrict__ rowstart,
                                             const int* __restrict__ edata,
                                             const uint32_t* __restrict__ hsb1,
                                             const float* __restrict__ dinv,
                                             const float* __restrict__ b1v,
                                             const float* __restrict__ W2,
                                             uint32_t* __restrict__ hsb2) {
    __shared__ float Wp[64 * 68];           // 17.4 KB, permuted rows
    const int tid = threadIdx.x;
    for (int f = tid; f < 64 * 64; f += 256) {
        int k = f >> 6, c = f & 63;
        int slot = ((k & 7) << 3) | (k >> 3);
        Wp[slot * 68 + c] = W2[f];
    }
    __syncthreads();

    const int node = blockIdx.x * 32 + (tid >> 3);
    const int lane = tid & 7;
    if (node >= N_NODES) return;

    // ---- gather phase (dims lane*8 .. lane*8+7) ----
    const int start = rowstart[node];
    const int end   = rowstart[node + 1];
    float a0 = 0.f, a1 = 0.f, a2 = 0.f, a3 = 0.f,
          a4 = 0.f, a5 = 0.f, a6 = 0.f, a7 = 0.f;
    const uint4* hq = (const uint4*)hsb1;
    for (int j = start; j < end; ++j) {
        int s = edata[j];
        const uint4 v = hq[(size_t)s * 8 + lane];
        a0 += bflo(v.x); a1 += bfhi(v.x);
        a2 += bflo(v.y); a3 += bfhi(v.y);
        a4 += bflo(v.z); a5 += bfhi(v.z);
        a6 += bflo(v.w); a7 += bfhi(v.w);
    }
    {
        const uint4 v = hq[(size_t)node * 8 + lane];
        a0 += bflo(v.x); a1 += bfhi(v.x);
        a2 += bflo(v.y); a3 += bfhi(v.y);
        a4 += bflo(v.z); a5 += bfhi(v.z);
        a6 += bflo(v.w); a7 += bfhi(v.w);
    }

    const float di = dinv[node];
    const float4 bb0 = *reinterpret_cast<const float4*>(&b1v[lane * 8]);
    const float4 bb1 = *reinterpret_cast<const float4*>(&b1v[lane * 8 + 4]);
    float r[8];
    r[0] = fmaxf(a0 * di + bb0.x, 0.f);
    r[1] = fmaxf(a1 * di + bb0.y, 0.f);
    r[2] = fmaxf(a2 * di + bb0.z, 0.f);
    r[3] = fmaxf(a3 * di + bb0.w, 0.f);
    r[4] = fmaxf(a4 * di + bb1.x, 0.f);
    r[5] = fmaxf(a5 * di + bb1.y, 0.f);
    r[6] = fmaxf(a6 * di + bb1.z, 0.f);
    r[7] = fmaxf(a7 * di + bb1.w, 0.f);

    // ---- inline GEMM: partials over this lane's 8 k's for all 64 cols ----
    float4 acc[16];
#pragma unroll
    for (int i = 0; i < 16; ++i) acc[i] = make_float4(0.f, 0.f, 0.f, 0.f);
#pragma unroll
    for (int kk = 0; kk < 8; ++kk) {
        const float rv = r[kk];
        const float4* wrow = (const float4*)&Wp[(kk * 8 + lane) * 68];
#pragma unroll
        for (int c = 0; c < 16; ++c) {
            const float4 w = wrow[c];
            acc[c].x += rv * w.x;
            acc[c].y += rv * w.y;
            acc[c].z += rv * w.z;
            acc[c].w += rv * w.w;
        }
    }

    // ---- 8-lane allreduce (xor 1,2,4) ----
#pragma unroll
    for (int m = 1; m <= 4; m <<= 1) {
#pragma unroll
        for (int i = 0; i < 16; ++i) {
            acc[i].x += __shfl_xor(acc[i].x, m, 64);
            acc[i].y += __shfl_xor(acc[i].y, m, 64);
            acc[i].z += __shfl_xor(acc[i].z, m, 64);
            acc[i].w += __shfl_xor(acc[i].w, m, 64);
        }
    }

    // ---- lane takes cols [lane*8, lane*8+8) = slots {2*lane, 2*lane+1} ----
    float4 lo, hi;
    switch (lane) {
        case 0: lo = acc[0];  hi = acc[1];  break;
        case 1: lo = acc[2];  hi = acc[3];  break;
        case 2: lo = acc[4];  hi = acc[5];  break;
        case 3: lo = acc[6];  hi = acc[7];  break;
        case 4: lo = acc[8];  hi = acc[9];  break;
        case 5: lo = acc[10]; hi = acc[11]; break;
        case 6: lo = acc[12]; hi = acc[13]; break;
        default: lo = acc[14]; hi = acc[15]; break;
    }
    uint4 o;
    o.x = pack2bf(lo.x * di, lo.y * di);
    o.y = pack2bf(lo.z * di, lo.w * di);
    o.z = pack2bf(hi.x * di, hi.y * di);
    o.w = pack2bf(hi.z * di, hi.w * di);
    ((uint4*)hsb2)[(size_t)node * 8 + lane] = o;
}

// ---------------------------------------------------------------------------
// k_gather: out[i] = dinv[i]*(sum_{j in N(i)} hs[j] + hs[i]) + b  (+ReLU)
// hs in bf16 (row = 32 uints = 128B). 8 lanes/node, 8 dims (1 uint4) each.
// ---------------------------------------------------------------------------
template <bool RELU>
__global__ __launch_bounds__(256) void k_gather(const int* __restrict__ rowstart,
                                                const int* __restrict__ edata,
                                                const uint32_t* __restrict__ hsb,
                                                const float* __restrict__ dinv,
                                                const float* __restrict__ bias,
                                                float* __restrict__ out) {
    int node = blockIdx.x * 32 + (threadIdx.x >> 3);
    int lane = threadIdx.x & 7;
    if (node >= N_NODES) return;

    int start = rowstart[node];
    int end   = rowstart[node + 1];

    float a0 = 0.f, a1 = 0.f, a2 = 0.f, a3 = 0.f,
          a4 = 0.f, a5 = 0.f, a6 = 0.f, a7 = 0.f;
    const uint4* hq = (const uint4*)hsb;

    for (int j = start; j < end; ++j) {
        int s = edata[j];
        const uint4 v = hq[(size_t)s * 8 + lane];
        a0 += bflo(v.x); a1 += bfhi(v.x);
        a2 += bflo(v.y); a3 += bfhi(v.y);
        a4 += bflo(v.z); a5 += bfhi(v.z);
        a6 += bflo(v.w); a7 += bfhi(v.w);
    }
    {
        const uint4 v = hq[(size_t)node * 8 + lane];
        a0 += bflo(v.x); a1 += bfhi(v.x);
        a2 += bflo(v.y); a3 += bfhi(v.y);
        a4 += bflo(v.z); a5 += bfhi(v.z);
        a6 += bflo(v.w); a7 += bfhi(v.w);
    }

    const float di = dinv[node];
    const float4 b0 = *reinterpret_cast<const float4*>(&bias[lane * 8]);
    const float4 b1 = *reinterpret_cast<const float4*>(&bias[lane * 8 + 4]);
    float4 o0, o1;
    o0.x = a0 * di + b0.x;  o0.y = a1 * di + b0.y;
    o0.z = a2 * di + b0.z;  o0.w = a3 * di + b0.w;
    o1.x = a4 * di + b1.x;  o1.y = a5 * di + b1.y;
    o1.z = a6 * di + b1.z;  o1.w = a7 * di + b1.w;
    if (RELU) {
        o0.x = fmaxf(o0.x, 0.f); o0.y = fmaxf(o0.y, 0.f);
        o0.z = fmaxf(o0.z, 0.f); o0.w = fmaxf(o0.w, 0.f);
        o1.x = fmaxf(o1.x, 0.f); o1.y = fmaxf(o1.y, 0.f);
        o1.z = fmaxf(o1.z, 0.f); o1.w = fmaxf(o1.w, 0.f);
    }
    float4* op = (float4*)&out[(size_t)node * 64 + lane * 8];
    op[0] = o0;
    op[1] = o1;
}

extern "C" void kernel_launch(void* const* d_in, const int* in_sizes, int n_in,
                              void* d_out, int out_size, void* d_ws, size_t ws_size,
                              hipStream_t stream) {
    const float* x  = (const float*)d_in[0];
    const int*   ei = (const int*)d_in[1];    // [2, N_EDGES] int32
    const float* W1 = (const float*)d_in[2];
    const float* b1 = (const float*)d_in[3];
    const float* W2 = (const float*)d_in[4];
    const float* b2 = (const float*)d_in[5];
    float* out = (float*)d_out;

    // Workspace carve-up (hsb1/hsb2/dinv 16B-aligned by construction):
    //   histT[NB*NPB] | bucketstart[NB+2] | brec[E] | rowstart[N+4] |
    //   edata[E] | dinv[N] | hsb1[N*32 u32] | hsb2[N*32 u32]
    int*      histT       = (int*)d_ws;
    int*      bucketstart = histT + NB * NPB;             // 25088
    int*      brec        = bucketstart + (NB + 2);       // +100
    int*      rowstart    = brec + N_EDGES;
    int*      edata       = rowstart + (N_NODES + 4);
    float*    dinv        = (float*)(edata + N_EDGES);
    uint32_t* hsb1        = (uint32_t*)(dinv + N_NODES);  // bf16 [N][64]
    uint32_t* hsb2        = hsb1 + (size_t)N_NODES * 32;  // bf16 [N][64]

    // --- CSR build (counting-sort partition) ---
    k_bhist<<<NPB, 256, 0, stream>>>(ei, histT);
    k_bscan<<<1, 256, 0, stream>>>(histT, bucketstart);
    k_part<<<NPB, 256, 0, stream>>>(ei, histT, brec);
    k_csr<<<NB, 256, 0, stream>>>(brec, bucketstart, rowstart, dinv, edata);

    // --- layer 1 GEMM ---
    k_gemm3<IN_DIM><<<(N_NODES + 63) / 64, 256, 0, stream>>>(x, W1, dinv, hsb1, N_NODES);
    // --- fused gather1 + ReLU + GEMM2 ---
    k_gw2<<<(N_NODES + 31) / 32, 256, 0, stream>>>(rowstart, edata, hsb1, dinv, b1, W2, hsb2);
    // --- layer 2 aggregate ---
    k_gather<false><<<(N_NODES + 31) / 32, 256, 0, stream>>>(rowstart, edata, hsb2, dinv, b2, out);
}

// Round 10
// 179.424 us; speedup vs baseline: 1.2540x; 1.2540x over previous
//
#include <hip/hip_runtime.h>
#include <stdint.h>

#define N_NODES 50000
#define N_EDGES 800000
#define IN_DIM  128
#define HID_DIM 64
#define OUT_DIM 64

#define NPB     256                         // partition blocks
#define EPB     (N_EDGES / NPB)             // 3125 edges per block (exact)
#define BSH     9                           // bucket shift: 512 nodes/bucket
#define NB      ((N_NODES + 511) >> BSH)    // 98 buckets

// ---------------------------------------------------------------------------
// bf16 helpers (RNE pack, bit-shift unpack; accumulate in fp32)
// ---------------------------------------------------------------------------
__device__ __forceinline__ uint32_t f2bf(float f) {
    uint32_t u = __float_as_uint(f);
    return (u + 0x7FFFu + ((u >> 16) & 1u)) >> 16;
}
__device__ __forceinline__ uint32_t pack2bf(float a, float b) {
    return f2bf(a) | (f2bf(b) << 16);
}
__device__ __forceinline__ float bflo(uint32_t v) { return __uint_as_float(v << 16); }
__device__ __forceinline__ float bfhi(uint32_t v) { return __uint_as_float(v & 0xFFFF0000u); }

// ---------------------------------------------------------------------------
// k_bhist: per-(block,bucket) histogram of dst. histT[bkt*NPB + blk].
// ---------------------------------------------------------------------------
__global__ __launch_bounds__(256) void k_bhist(const int* __restrict__ ei,
                                               int* __restrict__ histT) {
    __shared__ int hist[NB];
    const int blk = blockIdx.x, tid = threadIdx.x;
    if (tid < NB) hist[tid] = 0;
    __syncthreads();
    const int e0 = blk * EPB;
    for (int e = e0 + tid; e < e0 + EPB; e += 256)
        atomicAdd(&hist[ei[N_EDGES + e] >> BSH], 1);
    __syncthreads();
    if (tid < NB) histT[tid * NPB + blk] = hist[tid];
}

// ---------------------------------------------------------------------------
// k_bscan: single-block exclusive scan (in place) of histT[NB*NPB] in
// bucket-major order; emits bucketstart[NB+1].
// ---------------------------------------------------------------------------
__global__ __launch_bounds__(256) void k_bscan(int* __restrict__ histT,
                                               int* __restrict__ bucketstart) {
    const int t = threadIdx.x;
    const int CH = (NB * NPB) / 256;        // 98 contiguous elements per thread
    const int base = t * CH;
    int s = 0;
#pragma unroll 7
    for (int i = 0; i < CH; ++i) s += histT[base + i];

    int wid = t >> 6, lane = t & 63;
    int incl = s;
    for (int o = 1; o < 64; o <<= 1) {
        int v = __shfl_up(incl, o, 64);
        if (lane >= o) incl += v;
    }
    __shared__ int wt[4];
    if (lane == 63) wt[wid] = incl;
    __syncthreads();
    int woff = 0;
    for (int w = 0; w < wid; ++w) woff += wt[w];
    int excl = woff + incl - s;

#pragma unroll 7
    for (int i = 0; i < CH; ++i) {
        int v = histT[base + i];
        histT[base + i] = excl;
        excl += v;
    }
    __syncthreads();
    if (t < NB) bucketstart[t] = histT[t * NPB];
    if (t == 0) bucketstart[NB] = N_EDGES;
}

// ---------------------------------------------------------------------------
// k_part: re-stream edges; write rec = src | dlo<<16 into this block's
// reserved contiguous chunk of each bucket (coalesced-ish, XCD-friendly).
// ---------------------------------------------------------------------------
__global__ __launch_bounds__(256) void k_part(const int* __restrict__ ei,
                                              const int* __restrict__ histT,
                                              int* __restrict__ brec) {
    __shared__ int cursor[NB];
    const int blk = blockIdx.x, tid = threadIdx.x;
    if (tid < NB) cursor[tid] = histT[tid * NPB + blk];
    __syncthreads();
    const int e0 = blk * EPB;
    for (int e = e0 + tid; e < e0 + EPB; e += 256) {
        int s = ei[e];
        int d = ei[N_EDGES + e];
        int b = d >> BSH;
        int pos = atomicAdd(&cursor[b], 1);
        brec[pos] = s | ((d & 511) << 16);
    }
}

// ---------------------------------------------------------------------------
// k_csr: one block per bucket (512 nodes).  Counts per-node deg in LDS,
// block-scans to per-node offsets, emits rowstart & dinv (coalesced), then
// scatters final edata (src as ushort) — CSR region written by ONE wg/XCD.
// ---------------------------------------------------------------------------
__global__ __launch_bounds__(256) void k_csr(const int* __restrict__ brec,
                                             const int* __restrict__ bucketstart,
                                             int* __restrict__ rowstart,
                                             float* __restrict__ dinv,
                                             unsigned short* __restrict__ edata) {
    __shared__ int deg[512];
    __shared__ int segoff[512];
    __shared__ int wt[4];
    const int b = blockIdx.x, tid = threadIdx.x;
    const int lo = b << BSH;
    const int cstart = bucketstart[b];
    const int cend   = bucketstart[b + 1];

    deg[tid] = 0;
    deg[tid + 256] = 0;
    __syncthreads();

    for (int j = cstart + tid; j < cend; j += 256)
        atomicAdd(&deg[brec[j] >> 16], 1);
    __syncthreads();

    const int i0 = tid << 1;
    const int d0 = deg[i0], d1 = deg[i0 + 1];
    const int s = d0 + d1;
    int wid = tid >> 6, lane = tid & 63;
    int incl = s;
    for (int o = 1; o < 64; o <<= 1) {
        int v = __shfl_up(incl, o, 64);
        if (lane >= o) incl += v;
    }
    if (lane == 63) wt[wid] = incl;
    __syncthreads();
    int woff = 0;
    for (int w = 0; w < wid; ++w) woff += wt[w];
    const int excl = woff + incl - s;

    segoff[i0]     = excl;
    segoff[i0 + 1] = excl + d0;

    if (lo + i0 < N_NODES) {
        rowstart[lo + i0] = cstart + excl;
        dinv[lo + i0] = rsqrtf((float)d0 + 1.0f);
    }
    if (lo + i0 + 1 < N_NODES) {
        rowstart[lo + i0 + 1] = cstart + excl + d0;
        dinv[lo + i0 + 1] = rsqrtf((float)d1 + 1.0f);
    }
    if (b == NB - 1 && tid == 0) rowstart[N_NODES] = cend;
    __syncthreads();

    for (int j = cstart + tid; j < cend; j += 256) {
        int rec = brec[j];
        int pos = cstart + atomicAdd(&segoff[rec >> 16], 1);
        edata[pos] = (unsigned short)(rec & 0xFFFF);
    }
}

// ---------------------------------------------------------------------------
// k_gemm3: HSB[n,64] (bf16) = (X[n,K] @ W[K,64]) * dinv[row].
// ---------------------------------------------------------------------------
__device__ __forceinline__ void fma4(float4& acc, const float4& xv,
                                     const float4& w0, const float4& w1,
                                     const float4& w2, const float4& w3) {
    acc.x += xv.x * w0.x + xv.y * w1.x + xv.z * w2.x + xv.w * w3.x;
    acc.y += xv.x * w0.y + xv.y * w1.y + xv.z * w2.y + xv.w * w3.y;
    acc.z += xv.x * w0.z + xv.y * w1.z + xv.z * w2.z + xv.w * w3.z;
    acc.w += xv.x * w0.w + xv.y * w1.w + xv.z * w2.w + xv.w * w3.w;
}

__device__ __forceinline__ uint2 packbf4(const float4& a, float s) {
    return make_uint2(pack2bf(a.x * s, a.y * s), pack2bf(a.z * s, a.w * s));
}

template <int K>
__global__ __launch_bounds__(256) void k_gemm3(const float* __restrict__ X,
                                               const float* __restrict__ W,
                                               const float* __restrict__ dinv,
                                               uint32_t* __restrict__ HSB, int n) {
    constexpr int QK = K / 4;
    __shared__ float4 Ws[K * 16];
    const int tid = threadIdx.x;
    const int row0 = blockIdx.x * 64;

    for (int f = tid; f < K * 16; f += 256) Ws[f] = ((const float4*)W)[f];
    __syncthreads();

    const int c4 = tid & 15;
    const int r0 = row0 + ((tid >> 4) << 2);
    const float4* Xq = (const float4*)X;

    float4 a0 = make_float4(0.f, 0.f, 0.f, 0.f);
    float4 a1 = a0, a2 = a0, a3 = a0;

    if (r0 + 3 < n) {
        const float4* xp0 = Xq + (size_t)r0 * QK;
        const float4* xp1 = xp0 + QK;
        const float4* xp2 = xp1 + QK;
        const float4* xp3 = xp2 + QK;
#pragma unroll 4
        for (int k4 = 0; k4 < QK; ++k4) {
            const float4 x0 = xp0[k4];
            const float4 x1 = xp1[k4];
            const float4 x2 = xp2[k4];
            const float4 x3 = xp3[k4];
            const float4 w0 = Ws[(k4 * 4 + 0) * 16 + c4];
            const float4 w1 = Ws[(k4 * 4 + 1) * 16 + c4];
            const float4 w2 = Ws[(k4 * 4 + 2) * 16 + c4];
            const float4 w3 = Ws[(k4 * 4 + 3) * 16 + c4];
            fma4(a0, x0, w0, w1, w2, w3);
            fma4(a1, x1, w0, w1, w2, w3);
            fma4(a2, x2, w0, w1, w2, w3);
            fma4(a3, x3, w0, w1, w2, w3);
        }
        const float4 dv = ((const float4*)dinv)[r0 >> 2];
        ((uint2*)HSB)[((size_t)(r0 + 0) * 32 + c4 * 2) >> 1] = packbf4(a0, dv.x);
        ((uint2*)HSB)[((size_t)(r0 + 1) * 32 + c4 * 2) >> 1] = packbf4(a1, dv.y);
        ((uint2*)HSB)[((size_t)(r0 + 2) * 32 + c4 * 2) >> 1] = packbf4(a2, dv.z);
        ((uint2*)HSB)[((size_t)(r0 + 3) * 32 + c4 * 2) >> 1] = packbf4(a3, dv.w);
    } else {
        const float4 z = make_float4(0.f, 0.f, 0.f, 0.f);
        for (int k4 = 0; k4 < QK; ++k4) {
            const float4 x0 = (r0 + 0 < n) ? Xq[(size_t)(r0 + 0) * QK + k4] : z;
            const float4 x1 = (r0 + 1 < n) ? Xq[(size_t)(r0 + 1) * QK + k4] : z;
            const float4 x2 = (r0 + 2 < n) ? Xq[(size_t)(r0 + 2) * QK + k4] : z;
            const float4 x3 = (r0 + 3 < n) ? Xq[(size_t)(r0 + 3) * QK + k4] : z;
            const float4 w0 = Ws[(k4 * 4 + 0) * 16 + c4];
            const float4 w1 = Ws[(k4 * 4 + 1) * 16 + c4];
            const float4 w2 = Ws[(k4 * 4 + 2) * 16 + c4];
            const float4 w3 = Ws[(k4 * 4 + 3) * 16 + c4];
            fma4(a0, x0, w0, w1, w2, w3);
            fma4(a1, x1, w0, w1, w2, w3);
            fma4(a2, x2, w0, w1, w2, w3);
            fma4(a3, x3, w0, w1, w2, w3);
        }
        if (r0 + 0 < n) ((uint2*)HSB)[((size_t)(r0 + 0) * 32 + c4 * 2) >> 1] = packbf4(a0, dinv[r0 + 0]);
        if (r0 + 1 < n) ((uint2*)HSB)[((size_t)(r0 + 1) * 32 + c4 * 2) >> 1] = packbf4(a1, dinv[r0 + 1]);
        if (r0 + 2 < n) ((uint2*)HSB)[((size_t)(r0 + 2) * 32 + c4 * 2) >> 1] = packbf4(a2, dinv[r0 + 2]);
        if (r0 + 3 < n) ((uint2*)HSB)[((size_t)(r0 + 3) * 32 + c4 * 2) >> 1] = packbf4(a3, dinv[r0 + 3]);
    }
}

// ---------------------------------------------------------------------------
// k_gatherh: HALF-ROW gather pass.  Pass `half` reads only 32 of 64 dims
// (a 3.2 MB bf16 surface -> fits per-XCD L2, random reads become L2 hits).
// 4 lanes/node, one uint4 (8 bf16 dims) per lane per edge.
// out[i, half*32 + lane*8 ..] = dinv[i]*(sum hs[j] + hs[i]) + b  (+ReLU)
// ---------------------------------------------------------------------------
template <bool RELU>
__global__ __launch_bounds__(256) void k_gatherh(const int* __restrict__ rowstart,
                                                 const unsigned short* __restrict__ edata,
                                                 const uint32_t* __restrict__ hsb,
                                                 const float* __restrict__ dinv,
                                                 const float* __restrict__ bias,
                                                 float* __restrict__ out, int half) {
    int node = blockIdx.x * 64 + (threadIdx.x >> 2);
    int lane = threadIdx.x & 3;
    if (node >= N_NODES) return;

    int start = rowstart[node];
    int end   = rowstart[node + 1];

    const uint4* hq = (const uint4*)hsb;
    const int lq = half * 4 + lane;          // quad index within full row (8 quads)

    float a0 = 0.f, a1 = 0.f, a2 = 0.f, a3 = 0.f,
          a4 = 0.f, a5 = 0.f, a6 = 0.f, a7 = 0.f;

    for (int j = start; j < end; ++j) {
        int s = edata[j];
        const uint4 v = hq[(size_t)s * 8 + lq];
        a0 += bflo(v.x); a1 += bfhi(v.x);
        a2 += bflo(v.y); a3 += bfhi(v.y);
        a4 += bflo(v.z); a5 += bfhi(v.z);
        a6 += bflo(v.w); a7 += bfhi(v.w);
    }
    // self loop (hs already carries one dinv factor)
    {
        const uint4 v = hq[(size_t)node * 8 + lq];
        a0 += bflo(v.x); a1 += bfhi(v.x);
        a2 += bflo(v.y); a3 += bfhi(v.y);
        a4 += bflo(v.z); a5 += bfhi(v.z);
        a6 += bflo(v.w); a7 += bfhi(v.w);
    }

    const float di = dinv[node];
    const int dbase = half * 32 + lane * 8;
    const float4 b0 = *reinterpret_cast<const float4*>(&bias[dbase]);
    const float4 b1 = *reinterpret_cast<const float4*>(&bias[dbase + 4]);
    float4 o0, o1;
    o0.x = a0 * di + b0.x;  o0.y = a1 * di + b0.y;
    o0.z = a2 * di + b0.z;  o0.w = a3 * di + b0.w;
    o1.x = a4 * di + b1.x;  o1.y = a5 * di + b1.y;
    o1.z = a6 * di + b1.z;  o1.w = a7 * di + b1.w;
    if (RELU) {
        o0.x = fmaxf(o0.x, 0.f); o0.y = fmaxf(o0.y, 0.f);
        o0.z = fmaxf(o0.z, 0.f); o0.w = fmaxf(o0.w, 0.f);
        o1.x = fmaxf(o1.x, 0.f); o1.y = fmaxf(o1.y, 0.f);
        o1.z = fmaxf(o1.z, 0.f); o1.w = fmaxf(o1.w, 0.f);
    }
    float4* op = (float4*)&out[(size_t)node * 64 + dbase];
    op[0] = o0;
    op[1] = o1;
}

extern "C" void kernel_launch(void* const* d_in, const int* in_sizes, int n_in,
                              void* d_out, int out_size, void* d_ws, size_t ws_size,
                              hipStream_t stream) {
    const float* x  = (const float*)d_in[0];
    const int*   ei = (const int*)d_in[1];    // [2, N_EDGES] int32
    const float* W1 = (const float*)d_in[2];
    const float* b1 = (const float*)d_in[3];
    const float* W2 = (const float*)d_in[4];
    const float* b2 = (const float*)d_in[5];
    float* out = (float*)d_out;

    // Workspace carve-up (all offsets keep 16B alignment for float4/uint4):
    //   histT[25088] | bucketstart[100] | brec[E] | rowstart[N+4] |
    //   edata ushort[E] | dinv[N] | hsb1[N*32 u32] | a1[N*64 f32] | hsb2[N*32]
    int*            histT       = (int*)d_ws;
    int*            bucketstart = histT + NB * NPB;             // 25088
    int*            brec        = bucketstart + (NB + 2);       // +100
    int*            rowstart    = brec + N_EDGES;
    unsigned short* edata       = (unsigned short*)(rowstart + (N_NODES + 4));
    float*          dinv        = (float*)(edata + N_EDGES);    // E even -> aligned
    uint32_t*       hsb1        = (uint32_t*)(dinv + N_NODES);  // bf16 [N][64]
    float*          a1          = (float*)(hsb1 + (size_t)N_NODES * 32);
    uint32_t*       hsb2        = (uint32_t*)(a1 + (size_t)N_NODES * 64);

    // --- CSR build (counting-sort partition) ---
    k_bhist<<<NPB, 256, 0, stream>>>(ei, histT);
    k_bscan<<<1, 256, 0, stream>>>(histT, bucketstart);
    k_part<<<NPB, 256, 0, stream>>>(ei, histT, brec);
    k_csr<<<NB, 256, 0, stream>>>(brec, bucketstart, rowstart, dinv, edata);

    const int GG = (N_NODES + 63) / 64;   // 782 blocks per gather-half pass

    // --- layer 1 ---
    k_gemm3<IN_DIM><<<(N_NODES + 63) / 64, 256, 0, stream>>>(x, W1, dinv, hsb1, N_NODES);
    k_gatherh<true><<<GG, 256, 0, stream>>>(rowstart, edata, hsb1, dinv, b1, a1, 0);
    k_gatherh<true><<<GG, 256, 0, stream>>>(rowstart, edata, hsb1, dinv, b1, a1, 1);

    // --- layer 2 ---
    k_gemm3<HID_DIM><<<(N_NODES + 63) / 64, 256, 0, stream>>>(a1, W2, dinv, hsb2, N_NODES);
    k_gatherh<false><<<GG, 256, 0, stream>>>(rowstart, edata, hsb2, dinv, b2, out, 0);
    k_gatherh<false><<<GG, 256, 0, stream>>>(rowstart, edata, hsb2, dinv, b2, out, 1);
}

// Round 11
// 128.380 us; speedup vs baseline: 1.7525x; 1.3976x over previous
//
#include <hip/hip_runtime.h>
#include <stdint.h>

#define N_NODES 50000
#define N_EDGES 800000
#define IN_DIM  128
#define HID_DIM 64
#define OUT_DIM 64

#define NPB     256                         // partition blocks
#define EPB     (N_EDGES / NPB)             // 3125 edges per block (exact)
#define BSH     9                           // bucket shift: 512 nodes/bucket
#define NB      ((N_NODES + 511) >> BSH)    // 98 buckets

// ---------------------------------------------------------------------------
// bf16 helpers (RNE pack, bit-shift unpack; accumulate in fp32)
// ---------------------------------------------------------------------------
__device__ __forceinline__ uint32_t f2bf(float f) {
    uint32_t u = __float_as_uint(f);
    return (u + 0x7FFFu + ((u >> 16) & 1u)) >> 16;
}
__device__ __forceinline__ uint32_t pack2bf(float a, float b) {
    return f2bf(a) | (f2bf(b) << 16);
}
__device__ __forceinline__ float bflo(uint32_t v) { return __uint_as_float(v << 16); }
__device__ __forceinline__ float bfhi(uint32_t v) { return __uint_as_float(v & 0xFFFF0000u); }

// ---------------------------------------------------------------------------
// k_bhist: per-(block,bucket) histogram of dst. histT[bkt*NPB + blk].
// ---------------------------------------------------------------------------
__global__ __launch_bounds__(256) void k_bhist(const int* __restrict__ ei,
                                               int* __restrict__ histT) {
    __shared__ int hist[NB];
    const int blk = blockIdx.x, tid = threadIdx.x;
    if (tid < NB) hist[tid] = 0;
    __syncthreads();
    const int e0 = blk * EPB;
    for (int e = e0 + tid; e < e0 + EPB; e += 256)
        atomicAdd(&hist[ei[N_EDGES + e] >> BSH], 1);
    __syncthreads();
    if (tid < NB) histT[tid * NPB + blk] = hist[tid];
}

// ---------------------------------------------------------------------------
// k_bscan: single-block exclusive scan (in place) of histT[NB*NPB] in
// bucket-major order; emits bucketstart[NB+1].
// ---------------------------------------------------------------------------
__global__ __launch_bounds__(256) void k_bscan(int* __restrict__ histT,
                                               int* __restrict__ bucketstart) {
    const int t = threadIdx.x;
    const int CH = (NB * NPB) / 256;        // 98 contiguous elements per thread
    const int base = t * CH;
    int s = 0;
#pragma unroll 7
    for (int i = 0; i < CH; ++i) s += histT[base + i];

    int wid = t >> 6, lane = t & 63;
    int incl = s;
    for (int o = 1; o < 64; o <<= 1) {
        int v = __shfl_up(incl, o, 64);
        if (lane >= o) incl += v;
    }
    __shared__ int wt[4];
    if (lane == 63) wt[wid] = incl;
    __syncthreads();
    int woff = 0;
    for (int w = 0; w < wid; ++w) woff += wt[w];
    int excl = woff + incl - s;

#pragma unroll 7
    for (int i = 0; i < CH; ++i) {
        int v = histT[base + i];
        histT[base + i] = excl;
        excl += v;
    }
    __syncthreads();
    if (t < NB) bucketstart[t] = histT[t * NPB];
    if (t == 0) bucketstart[NB] = N_EDGES;
}

// ---------------------------------------------------------------------------
// k_part: re-stream edges; write rec = src | dlo<<16 into this block's
// reserved contiguous chunk of each bucket (coalesced-ish, XCD-friendly).
// ---------------------------------------------------------------------------
__global__ __launch_bounds__(256) void k_part(const int* __restrict__ ei,
                                              const int* __restrict__ histT,
                                              int* __restrict__ brec) {
    __shared__ int cursor[NB];
    const int blk = blockIdx.x, tid = threadIdx.x;
    if (tid < NB) cursor[tid] = histT[tid * NPB + blk];
    __syncthreads();
    const int e0 = blk * EPB;
    for (int e = e0 + tid; e < e0 + EPB; e += 256) {
        int s = ei[e];
        int d = ei[N_EDGES + e];
        int b = d >> BSH;
        int pos = atomicAdd(&cursor[b], 1);
        brec[pos] = s | ((d & 511) << 16);
    }
}

// ---------------------------------------------------------------------------
// k_csr: one block per bucket (512 nodes).  Counts per-node deg in LDS,
// block-scans to per-node offsets, emits rowstart & dinv (coalesced), then
// scatters final edata (src as ushort) — CSR region written by ONE wg/XCD.
// ---------------------------------------------------------------------------
__global__ __launch_bounds__(256) void k_csr(const int* __restrict__ brec,
                                             const int* __restrict__ bucketstart,
                                             int* __restrict__ rowstart,
                                             float* __restrict__ dinv,
                                             unsigned short* __restrict__ edata) {
    __shared__ int deg[512];
    __shared__ int segoff[512];
    __shared__ int wt[4];
    const int b = blockIdx.x, tid = threadIdx.x;
    const int lo = b << BSH;
    const int cstart = bucketstart[b];
    const int cend   = bucketstart[b + 1];

    deg[tid] = 0;
    deg[tid + 256] = 0;
    __syncthreads();

    for (int j = cstart + tid; j < cend; j += 256)
        atomicAdd(&deg[brec[j] >> 16], 1);
    __syncthreads();

    const int i0 = tid << 1;
    const int d0 = deg[i0], d1 = deg[i0 + 1];
    const int s = d0 + d1;
    int wid = tid >> 6, lane = tid & 63;
    int incl = s;
    for (int o = 1; o < 64; o <<= 1) {
        int v = __shfl_up(incl, o, 64);
        if (lane >= o) incl += v;
    }
    if (lane == 63) wt[wid] = incl;
    __syncthreads();
    int woff = 0;
    for (int w = 0; w < wid; ++w) woff += wt[w];
    const int excl = woff + incl - s;

    segoff[i0]     = excl;
    segoff[i0 + 1] = excl + d0;

    if (lo + i0 < N_NODES) {
        rowstart[lo + i0] = cstart + excl;
        dinv[lo + i0] = rsqrtf((float)d0 + 1.0f);
    }
    if (lo + i0 + 1 < N_NODES) {
        rowstart[lo + i0 + 1] = cstart + excl + d0;
        dinv[lo + i0 + 1] = rsqrtf((float)d1 + 1.0f);
    }
    if (b == NB - 1 && tid == 0) rowstart[N_NODES] = cend;
    __syncthreads();

    for (int j = cstart + tid; j < cend; j += 256) {
        int rec = brec[j];
        int pos = cstart + atomicAdd(&segoff[rec >> 16], 1);
        edata[pos] = (unsigned short)(rec & 0xFFFF);
    }
}

// ---------------------------------------------------------------------------
// k_gemm3: HSB[n,64] (bf16) = (X[n,K] @ W[K,64]) * dinv[row].
// ---------------------------------------------------------------------------
__device__ __forceinline__ void fma4(float4& acc, const float4& xv,
                                     const float4& w0, const float4& w1,
                                     const float4& w2, const float4& w3) {
    acc.x += xv.x * w0.x + xv.y * w1.x + xv.z * w2.x + xv.w * w3.x;
    acc.y += xv.x * w0.y + xv.y * w1.y + xv.z * w2.y + xv.w * w3.y;
    acc.z += xv.x * w0.z + xv.y * w1.z + xv.z * w2.z + xv.w * w3.z;
    acc.w += xv.x * w0.w + xv.y * w1.w + xv.z * w2.w + xv.w * w3.w;
}

__device__ __forceinline__ uint2 packbf4(const float4& a, float s) {
    return make_uint2(pack2bf(a.x * s, a.y * s), pack2bf(a.z * s, a.w * s));
}

template <int K>
__global__ __launch_bounds__(256) void k_gemm3(const float* __restrict__ X,
                                               const float* __restrict__ W,
                                               const float* __restrict__ dinv,
                                               uint32_t* __restrict__ HSB, int n) {
    constexpr int QK = K / 4;
    __shared__ float4 Ws[K * 16];
    const int tid = threadIdx.x;
    const int row0 = blockIdx.x * 64;

    for (int f = tid; f < K * 16; f += 256) Ws[f] = ((const float4*)W)[f];
    __syncthreads();

    const int c4 = tid & 15;
    const int r0 = row0 + ((tid >> 4) << 2);
    const float4* Xq = (const float4*)X;

    float4 a0 = make_float4(0.f, 0.f, 0.f, 0.f);
    float4 a1 = a0, a2 = a0, a3 = a0;

    if (r0 + 3 < n) {
        const float4* xp0 = Xq + (size_t)r0 * QK;
        const float4* xp1 = xp0 + QK;
        const float4* xp2 = xp1 + QK;
        const float4* xp3 = xp2 + QK;
#pragma unroll 4
        for (int k4 = 0; k4 < QK; ++k4) {
            const float4 x0 = xp0[k4];
            const float4 x1 = xp1[k4];
            const float4 x2 = xp2[k4];
            const float4 x3 = xp3[k4];
            const float4 w0 = Ws[(k4 * 4 + 0) * 16 + c4];
            const float4 w1 = Ws[(k4 * 4 + 1) * 16 + c4];
            const float4 w2 = Ws[(k4 * 4 + 2) * 16 + c4];
            const float4 w3 = Ws[(k4 * 4 + 3) * 16 + c4];
            fma4(a0, x0, w0, w1, w2, w3);
            fma4(a1, x1, w0, w1, w2, w3);
            fma4(a2, x2, w0, w1, w2, w3);
            fma4(a3, x3, w0, w1, w2, w3);
        }
        const float4 dv = ((const float4*)dinv)[r0 >> 2];
        ((uint2*)HSB)[((size_t)(r0 + 0) * 32 + c4 * 2) >> 1] = packbf4(a0, dv.x);
        ((uint2*)HSB)[((size_t)(r0 + 1) * 32 + c4 * 2) >> 1] = packbf4(a1, dv.y);
        ((uint2*)HSB)[((size_t)(r0 + 2) * 32 + c4 * 2) >> 1] = packbf4(a2, dv.z);
        ((uint2*)HSB)[((size_t)(r0 + 3) * 32 + c4 * 2) >> 1] = packbf4(a3, dv.w);
    } else {
        const float4 z = make_float4(0.f, 0.f, 0.f, 0.f);
        for (int k4 = 0; k4 < QK; ++k4) {
            const float4 x0 = (r0 + 0 < n) ? Xq[(size_t)(r0 + 0) * QK + k4] : z;
            const float4 x1 = (r0 + 1 < n) ? Xq[(size_t)(r0 + 1) * QK + k4] : z;
            const float4 x2 = (r0 + 2 < n) ? Xq[(size_t)(r0 + 2) * QK + k4] : z;
            const float4 x3 = (r0 + 3 < n) ? Xq[(size_t)(r0 + 3) * QK + k4] : z;
            const float4 w0 = Ws[(k4 * 4 + 0) * 16 + c4];
            const float4 w1 = Ws[(k4 * 4 + 1) * 16 + c4];
            const float4 w2 = Ws[(k4 * 4 + 2) * 16 + c4];
            const float4 w3 = Ws[(k4 * 4 + 3) * 16 + c4];
            fma4(a0, x0, w0, w1, w2, w3);
            fma4(a1, x1, w0, w1, w2, w3);
            fma4(a2, x2, w0, w1, w2, w3);
            fma4(a3, x3, w0, w1, w2, w3);
        }
        if (r0 + 0 < n) ((uint2*)HSB)[((size_t)(r0 + 0) * 32 + c4 * 2) >> 1] = packbf4(a0, dinv[r0 + 0]);
        if (r0 + 1 < n) ((uint2*)HSB)[((size_t)(r0 + 1) * 32 + c4 * 2) >> 1] = packbf4(a1, dinv[r0 + 1]);
        if (r0 + 2 < n) ((uint2*)HSB)[((size_t)(r0 + 2) * 32 + c4 * 2) >> 1] = packbf4(a2, dinv[r0 + 2]);
        if (r0 + 3 < n) ((uint2*)HSB)[((size_t)(r0 + 3) * 32 + c4 * 2) >> 1] = packbf4(a3, dinv[r0 + 3]);
    }
}

// ---------------------------------------------------------------------------
// k_gather: full-row CSR gather, UNROLL-4 for memory-level parallelism.
// 8 lanes/node, one uint4 (8 bf16 dims) per lane per edge; 4 independent
// edge loads in flight per thread before any accumulate.
// out[i] = dinv[i]*(sum_{j in N(i)} hs[j] + hs[i]) + b   (+ReLU)
// ---------------------------------------------------------------------------
template <bool RELU>
__global__ __launch_bounds__(256) void k_gather(const int* __restrict__ rowstart,
                                                const unsigned short* __restrict__ edata,
                                                const uint32_t* __restrict__ hsb,
                                                const float* __restrict__ dinv,
                                                const float* __restrict__ bias,
                                                float* __restrict__ out) {
    int node = blockIdx.x * 32 + (threadIdx.x >> 3);
    int lane = threadIdx.x & 7;
    if (node >= N_NODES) return;

    int start = rowstart[node];
    int end   = rowstart[node + 1];

    const uint4* hq = (const uint4*)hsb;
    float a0 = 0.f, a1 = 0.f, a2 = 0.f, a3 = 0.f,
          a4 = 0.f, a5 = 0.f, a6 = 0.f, a7 = 0.f;

    int j = start;
    for (; j + 4 <= end; j += 4) {
        const int s0 = edata[j + 0];
        const int s1 = edata[j + 1];
        const int s2 = edata[j + 2];
        const int s3 = edata[j + 3];
        const uint4 v0 = hq[(size_t)s0 * 8 + lane];
        const uint4 v1 = hq[(size_t)s1 * 8 + lane];
        const uint4 v2 = hq[(size_t)s2 * 8 + lane];
        const uint4 v3 = hq[(size_t)s3 * 8 + lane];
        a0 += (bflo(v0.x) + bflo(v1.x)) + (bflo(v2.x) + bflo(v3.x));
        a1 += (bfhi(v0.x) + bfhi(v1.x)) + (bfhi(v2.x) + bfhi(v3.x));
        a2 += (bflo(v0.y) + bflo(v1.y)) + (bflo(v2.y) + bflo(v3.y));
        a3 += (bfhi(v0.y) + bfhi(v1.y)) + (bfhi(v2.y) + bfhi(v3.y));
        a4 += (bflo(v0.z) + bflo(v1.z)) + (bflo(v2.z) + bflo(v3.z));
        a5 += (bfhi(v0.z) + bfhi(v1.z)) + (bfhi(v2.z) + bfhi(v3.z));
        a6 += (bflo(v0.w) + bflo(v1.w)) + (bflo(v2.w) + bflo(v3.w));
        a7 += (bfhi(v0.w) + bfhi(v1.w)) + (bfhi(v2.w) + bfhi(v3.w));
    }
    for (; j < end; ++j) {
        const int s = edata[j];
        const uint4 v = hq[(size_t)s * 8 + lane];
        a0 += bflo(v.x); a1 += bfhi(v.x);
        a2 += bflo(v.y); a3 += bfhi(v.y);
        a4 += bflo(v.z); a5 += bfhi(v.z);
        a6 += bflo(v.w); a7 += bfhi(v.w);
    }
    // self loop (hs already carries one dinv factor)
    {
        const uint4 v = hq[(size_t)node * 8 + lane];
        a0 += bflo(v.x); a1 += bfhi(v.x);
        a2 += bflo(v.y); a3 += bfhi(v.y);
        a4 += bflo(v.z); a5 += bfhi(v.z);
        a6 += bflo(v.w); a7 += bfhi(v.w);
    }

    const float di = dinv[node];
    const float4 b0 = *reinterpret_cast<const float4*>(&bias[lane * 8]);
    const float4 b1 = *reinterpret_cast<const float4*>(&bias[lane * 8 + 4]);
    float4 o0, o1;
    o0.x = a0 * di + b0.x;  o0.y = a1 * di + b0.y;
    o0.z = a2 * di + b0.z;  o0.w = a3 * di + b0.w;
    o1.x = a4 * di + b1.x;  o1.y = a5 * di + b1.y;
    o1.z = a6 * di + b1.z;  o1.w = a7 * di + b1.w;
    if (RELU) {
        o0.x = fmaxf(o0.x, 0.f); o0.y = fmaxf(o0.y, 0.f);
        o0.z = fmaxf(o0.z, 0.f); o0.w = fmaxf(o0.w, 0.f);
        o1.x = fmaxf(o1.x, 0.f); o1.y = fmaxf(o1.y, 0.f);
        o1.z = fmaxf(o1.z, 0.f); o1.w = fmaxf(o1.w, 0.f);
    }
    float4* op = (float4*)&out[(size_t)node * 64 + lane * 8];
    op[0] = o0;
    op[1] = o1;
}

extern "C" void kernel_launch(void* const* d_in, const int* in_sizes, int n_in,
                              void* d_out, int out_size, void* d_ws, size_t ws_size,
                              hipStream_t stream) {
    const float* x  = (const float*)d_in[0];
    const int*   ei = (const int*)d_in[1];    // [2, N_EDGES] int32
    const float* W1 = (const float*)d_in[2];
    const float* b1 = (const float*)d_in[3];
    const float* W2 = (const float*)d_in[4];
    const float* b2 = (const float*)d_in[5];
    float* out = (float*)d_out;

    // Workspace carve-up (all offsets keep 16B alignment for float4/uint4):
    //   histT[25088] | bucketstart[100] | brec[E] | rowstart[N+4] |
    //   edata ushort[E] | dinv[N] | hsb1[N*32 u32] | a1[N*64 f32] | hsb2[N*32]
    int*            histT       = (int*)d_ws;
    int*            bucketstart = histT + NB * NPB;             // 25088
    int*            brec        = bucketstart + (NB + 2);       // +100
    int*            rowstart    = brec + N_EDGES;
    unsigned short* edata       = (unsigned short*)(rowstart + (N_NODES + 4));
    float*          dinv        = (float*)(edata + N_EDGES);    // E even -> aligned
    uint32_t*       hsb1        = (uint32_t*)(dinv + N_NODES);  // bf16 [N][64]
    float*          a1          = (float*)(hsb1 + (size_t)N_NODES * 32);
    uint32_t*       hsb2        = (uint32_t*)(a1 + (size_t)N_NODES * 64);

    // --- CSR build (counting-sort partition) ---
    k_bhist<<<NPB, 256, 0, stream>>>(ei, histT);
    k_bscan<<<1, 256, 0, stream>>>(histT, bucketstart);
    k_part<<<NPB, 256, 0, stream>>>(ei, histT, brec);
    k_csr<<<NB, 256, 0, stream>>>(brec, bucketstart, rowstart, dinv, edata);

    const int GG = (N_NODES + 31) / 32;   // 1563 blocks per gather pass

    // --- layer 1 ---
    k_gemm3<IN_DIM><<<(N_NODES + 63) / 64, 256, 0, stream>>>(x, W1, dinv, hsb1, N_NODES);
    k_gather<true><<<GG, 256, 0, stream>>>(rowstart, edata, hsb1, dinv, b1, a1);

    // --- layer 2 ---
    k_gemm3<HID_DIM><<<(N_NODES + 63) / 64, 256, 0, stream>>>(a1, W2, dinv, hsb2, N_NODES);
    k_gather<false><<<GG, 256, 0, stream>>>(rowstart, edata, hsb2, dinv, b2, out);
}

// Round 12
// 119.427 us; speedup vs baseline: 1.8839x; 1.0750x over previous
//
#include <hip/hip_runtime.h>
#include <stdint.h>

#define N_NODES 50000
#define N_EDGES 800000
#define IN_DIM  128
#define HID_DIM 64
#define OUT_DIM 64

#define NPB     256                         // partition blocks
#define EPB     (N_EDGES / NPB)             // 3125 edges per block (exact)
#define BSH     9                           // bucket shift: 512 nodes/bucket
#define NB      ((N_NODES + 511) >> BSH)    // 98 buckets
#define CSR_CAP 12288                       // LDS-staged edges per bucket (48KB)

// ---------------------------------------------------------------------------
// bf16 helpers (RNE pack, bit-shift unpack; accumulate in fp32)
// ---------------------------------------------------------------------------
__device__ __forceinline__ uint32_t f2bf(float f) {
    uint32_t u = __float_as_uint(f);
    return (u + 0x7FFFu + ((u >> 16) & 1u)) >> 16;
}
__device__ __forceinline__ uint32_t pack2bf(float a, float b) {
    return f2bf(a) | (f2bf(b) << 16);
}
__device__ __forceinline__ float bflo(uint32_t v) { return __uint_as_float(v << 16); }
__device__ __forceinline__ float bfhi(uint32_t v) { return __uint_as_float(v & 0xFFFF0000u); }

// ---------------------------------------------------------------------------
// k_bhist: per-(block,bucket) histogram of dst. histT[bkt*NPB + blk].
// ---------------------------------------------------------------------------
__global__ __launch_bounds__(256) void k_bhist(const int* __restrict__ ei,
                                               int* __restrict__ histT) {
    __shared__ int hist[NB];
    const int blk = blockIdx.x, tid = threadIdx.x;
    if (tid < NB) hist[tid] = 0;
    __syncthreads();
    const int e0 = blk * EPB;
    for (int e = e0 + tid; e < e0 + EPB; e += 256)
        atomicAdd(&hist[ei[N_EDGES + e] >> BSH], 1);
    __syncthreads();
    if (tid < NB) histT[tid * NPB + blk] = hist[tid];
}

// ---------------------------------------------------------------------------
// k_bscan: single-block exclusive scan (in place) of histT[NB*NPB] in
// bucket-major order; emits bucketstart[NB+1].
// ---------------------------------------------------------------------------
__global__ __launch_bounds__(256) void k_bscan(int* __restrict__ histT,
                                               int* __restrict__ bucketstart) {
    const int t = threadIdx.x;
    const int CH = (NB * NPB) / 256;        // 98 contiguous elements per thread
    const int base = t * CH;
    int s = 0;
#pragma unroll 7
    for (int i = 0; i < CH; ++i) s += histT[base + i];

    int wid = t >> 6, lane = t & 63;
    int incl = s;
    for (int o = 1; o < 64; o <<= 1) {
        int v = __shfl_up(incl, o, 64);
        if (lane >= o) incl += v;
    }
    __shared__ int wt[4];
    if (lane == 63) wt[wid] = incl;
    __syncthreads();
    int woff = 0;
    for (int w = 0; w < wid; ++w) woff += wt[w];
    int excl = woff + incl - s;

#pragma unroll 7
    for (int i = 0; i < CH; ++i) {
        int v = histT[base + i];
        histT[base + i] = excl;
        excl += v;
    }
    __syncthreads();
    if (t < NB) bucketstart[t] = histT[t * NPB];
    if (t == 0) bucketstart[NB] = N_EDGES;
}

// ---------------------------------------------------------------------------
// k_part: re-stream edges; write rec = src | dlo<<16 into this block's
// reserved contiguous chunk of each bucket (coalesced-ish, XCD-friendly).
// ---------------------------------------------------------------------------
__global__ __launch_bounds__(256) void k_part(const int* __restrict__ ei,
                                              const int* __restrict__ histT,
                                              int* __restrict__ brec) {
    __shared__ int cursor[NB];
    const int blk = blockIdx.x, tid = threadIdx.x;
    if (tid < NB) cursor[tid] = histT[tid * NPB + blk];
    __syncthreads();
    const int e0 = blk * EPB;
    for (int e = e0 + tid; e < e0 + EPB; e += 256) {
        int s = ei[e];
        int d = ei[N_EDGES + e];
        int b = d >> BSH;
        int pos = atomicAdd(&cursor[b], 1);
        brec[pos] = s | ((d & 511) << 16);
    }
}

// ---------------------------------------------------------------------------
// k_csr: one block per bucket (512 nodes).  Stages the bucket's brec chunk
// in LDS once (fallback to global if oversized), counts per-node deg,
// block-scans, emits rowstart & dinv, scatters edata (src ushort).
// ---------------------------------------------------------------------------
__global__ __launch_bounds__(256) void k_csr(const int* __restrict__ brec,
                                             const int* __restrict__ bucketstart,
                                             int* __restrict__ rowstart,
                                             float* __restrict__ dinv,
                                             unsigned short* __restrict__ edata) {
    __shared__ int deg[512];
    __shared__ int segoff[512];
    __shared__ int wt[4];
    __shared__ int sbuf[CSR_CAP];
    const int b = blockIdx.x, tid = threadIdx.x;
    const int lo = b << BSH;
    const int cstart = bucketstart[b];
    const int cend   = bucketstart[b + 1];
    const int cnt    = cend - cstart;
    const bool fit   = (cnt <= CSR_CAP);

    deg[tid] = 0;
    deg[tid + 256] = 0;
    if (fit) {
        for (int j = tid; j < cnt; j += 256) sbuf[j] = brec[cstart + j];
    }
    __syncthreads();

    // pass 1: per-node degree
    if (fit) {
        for (int j = tid; j < cnt; j += 256) atomicAdd(&deg[sbuf[j] >> 16], 1);
    } else {
        for (int j = cstart + tid; j < cend; j += 256) atomicAdd(&deg[brec[j] >> 16], 1);
    }
    __syncthreads();

    const int i0 = tid << 1;
    const int d0 = deg[i0], d1 = deg[i0 + 1];
    const int s = d0 + d1;
    int wid = tid >> 6, lane = tid & 63;
    int incl = s;
    for (int o = 1; o < 64; o <<= 1) {
        int v = __shfl_up(incl, o, 64);
        if (lane >= o) incl += v;
    }
    if (lane == 63) wt[wid] = incl;
    __syncthreads();
    int woff = 0;
    for (int w = 0; w < wid; ++w) woff += wt[w];
    const int excl = woff + incl - s;

    segoff[i0]     = excl;
    segoff[i0 + 1] = excl + d0;

    if (lo + i0 < N_NODES) {
        rowstart[lo + i0] = cstart + excl;
        dinv[lo + i0] = rsqrtf((float)d0 + 1.0f);
    }
    if (lo + i0 + 1 < N_NODES) {
        rowstart[lo + i0 + 1] = cstart + excl + d0;
        dinv[lo + i0 + 1] = rsqrtf((float)d1 + 1.0f);
    }
    if (b == NB - 1 && tid == 0) rowstart[N_NODES] = cend;
    __syncthreads();

    // pass 2: scatter into final CSR slots
    if (fit) {
        for (int j = tid; j < cnt; j += 256) {
            int rec = sbuf[j];
            int pos = cstart + atomicAdd(&segoff[rec >> 16], 1);
            edata[pos] = (unsigned short)(rec & 0xFFFF);
        }
    } else {
        for (int j = cstart + tid; j < cend; j += 256) {
            int rec = brec[j];
            int pos = cstart + atomicAdd(&segoff[rec >> 16], 1);
            edata[pos] = (unsigned short)(rec & 0xFFFF);
        }
    }
}

// ---------------------------------------------------------------------------
// k_gemm3: HSB[n,64] (bf16) = (X[n,K] @ W[K,64]) * dinv[row].
// ---------------------------------------------------------------------------
__device__ __forceinline__ void fma4(float4& acc, const float4& xv,
                                     const float4& w0, const float4& w1,
                                     const float4& w2, const float4& w3) {
    acc.x += xv.x * w0.x + xv.y * w1.x + xv.z * w2.x + xv.w * w3.x;
    acc.y += xv.x * w0.y + xv.y * w1.y + xv.z * w2.y + xv.w * w3.y;
    acc.z += xv.x * w0.z + xv.y * w1.z + xv.z * w2.z + xv.w * w3.z;
    acc.w += xv.x * w0.w + xv.y * w1.w + xv.z * w2.w + xv.w * w3.w;
}

__device__ __forceinline__ uint2 packbf4(const float4& a, float s) {
    return make_uint2(pack2bf(a.x * s, a.y * s), pack2bf(a.z * s, a.w * s));
}

template <int K>
__global__ __launch_bounds__(256) void k_gemm3(const float* __restrict__ X,
                                               const float* __restrict__ W,
                                               const float* __restrict__ dinv,
                                               uint32_t* __restrict__ HSB, int n) {
    constexpr int QK = K / 4;
    __shared__ float4 Ws[K * 16];
    const int tid = threadIdx.x;
    const int row0 = blockIdx.x * 64;

    for (int f = tid; f < K * 16; f += 256) Ws[f] = ((const float4*)W)[f];
    __syncthreads();

    const int c4 = tid & 15;
    const int r0 = row0 + ((tid >> 4) << 2);
    const float4* Xq = (const float4*)X;

    float4 a0 = make_float4(0.f, 0.f, 0.f, 0.f);
    float4 a1 = a0, a2 = a0, a3 = a0;

    if (r0 + 3 < n) {
        const float4* xp0 = Xq + (size_t)r0 * QK;
        const float4* xp1 = xp0 + QK;
        const float4* xp2 = xp1 + QK;
        const float4* xp3 = xp2 + QK;
#pragma unroll 4
        for (int k4 = 0; k4 < QK; ++k4) {
            const float4 x0 = xp0[k4];
            const float4 x1 = xp1[k4];
            const float4 x2 = xp2[k4];
            const float4 x3 = xp3[k4];
            const float4 w0 = Ws[(k4 * 4 + 0) * 16 + c4];
            const float4 w1 = Ws[(k4 * 4 + 1) * 16 + c4];
            const float4 w2 = Ws[(k4 * 4 + 2) * 16 + c4];
            const float4 w3 = Ws[(k4 * 4 + 3) * 16 + c4];
            fma4(a0, x0, w0, w1, w2, w3);
            fma4(a1, x1, w0, w1, w2, w3);
            fma4(a2, x2, w0, w1, w2, w3);
            fma4(a3, x3, w0, w1, w2, w3);
        }
        const float4 dv = ((const float4*)dinv)[r0 >> 2];
        ((uint2*)HSB)[((size_t)(r0 + 0) * 32 + c4 * 2) >> 1] = packbf4(a0, dv.x);
        ((uint2*)HSB)[((size_t)(r0 + 1) * 32 + c4 * 2) >> 1] = packbf4(a1, dv.y);
        ((uint2*)HSB)[((size_t)(r0 + 2) * 32 + c4 * 2) >> 1] = packbf4(a2, dv.z);
        ((uint2*)HSB)[((size_t)(r0 + 3) * 32 + c4 * 2) >> 1] = packbf4(a3, dv.w);
    } else {
        const float4 z = make_float4(0.f, 0.f, 0.f, 0.f);
        for (int k4 = 0; k4 < QK; ++k4) {
            const float4 x0 = (r0 + 0 < n) ? Xq[(size_t)(r0 + 0) * QK + k4] : z;
            const float4 x1 = (r0 + 1 < n) ? Xq[(size_t)(r0 + 1) * QK + k4] : z;
            const float4 x2 = (r0 + 2 < n) ? Xq[(size_t)(r0 + 2) * QK + k4] : z;
            const float4 x3 = (r0 + 3 < n) ? Xq[(size_t)(r0 + 3) * QK + k4] : z;
            const float4 w0 = Ws[(k4 * 4 + 0) * 16 + c4];
            const float4 w1 = Ws[(k4 * 4 + 1) * 16 + c4];
            const float4 w2 = Ws[(k4 * 4 + 2) * 16 + c4];
            const float4 w3 = Ws[(k4 * 4 + 3) * 16 + c4];
            fma4(a0, x0, w0, w1, w2, w3);
            fma4(a1, x1, w0, w1, w2, w3);
            fma4(a2, x2, w0, w1, w2, w3);
            fma4(a3, x3, w0, w1, w2, w3);
        }
        if (r0 + 0 < n) ((uint2*)HSB)[((size_t)(r0 + 0) * 32 + c4 * 2) >> 1] = packbf4(a0, dinv[r0 + 0]);
        if (r0 + 1 < n) ((uint2*)HSB)[((size_t)(r0 + 1) * 32 + c4 * 2) >> 1] = packbf4(a1, dinv[r0 + 1]);
        if (r0 + 2 < n) ((uint2*)HSB)[((size_t)(r0 + 2) * 32 + c4 * 2) >> 1] = packbf4(a2, dinv[r0 + 2]);
        if (r0 + 3 < n) ((uint2*)HSB)[((size_t)(r0 + 3) * 32 + c4 * 2) >> 1] = packbf4(a3, dinv[r0 + 3]);
    }
}

// ---------------------------------------------------------------------------
// k_gather: full-row CSR gather, UNROLL-8 for memory-level parallelism.
// 8 lanes/node, one uint4 (8 bf16 dims) per lane per edge; 8 independent
// edge loads in flight per thread before any accumulate.
// out[i] = dinv[i]*(sum_{j in N(i)} hs[j] + hs[i]) + b   (+ReLU)
// ---------------------------------------------------------------------------
template <bool RELU>
__global__ __launch_bounds__(256) void k_gather(const int* __restrict__ rowstart,
                                                const unsigned short* __restrict__ edata,
                                                const uint32_t* __restrict__ hsb,
                                                const float* __restrict__ dinv,
                                                const float* __restrict__ bias,
                                                float* __restrict__ out) {
    int node = blockIdx.x * 32 + (threadIdx.x >> 3);
    int lane = threadIdx.x & 7;
    if (node >= N_NODES) return;

    int start = rowstart[node];
    int end   = rowstart[node + 1];

    const uint4* hq = (const uint4*)hsb;
    float a0 = 0.f, a1 = 0.f, a2 = 0.f, a3 = 0.f,
          a4 = 0.f, a5 = 0.f, a6 = 0.f, a7 = 0.f;

    int j = start;
    for (; j + 8 <= end; j += 8) {
        const int s0 = edata[j + 0];
        const int s1 = edata[j + 1];
        const int s2 = edata[j + 2];
        const int s3 = edata[j + 3];
        const int s4 = edata[j + 4];
        const int s5 = edata[j + 5];
        const int s6 = edata[j + 6];
        const int s7 = edata[j + 7];
        const uint4 v0 = hq[(size_t)s0 * 8 + lane];
        const uint4 v1 = hq[(size_t)s1 * 8 + lane];
        const uint4 v2 = hq[(size_t)s2 * 8 + lane];
        const uint4 v3 = hq[(size_t)s3 * 8 + lane];
        const uint4 v4 = hq[(size_t)s4 * 8 + lane];
        const uint4 v5 = hq[(size_t)s5 * 8 + lane];
        const uint4 v6 = hq[(size_t)s6 * 8 + lane];
        const uint4 v7 = hq[(size_t)s7 * 8 + lane];
        a0 += ((bflo(v0.x) + bflo(v1.x)) + (bflo(v2.x) + bflo(v3.x)))
            + ((bflo(v4.x) + bflo(v5.x)) + (bflo(v6.x) + bflo(v7.x)));
        a1 += ((bfhi(v0.x) + bfhi(v1.x)) + (bfhi(v2.x) + bfhi(v3.x)))
            + ((bfhi(v4.x) + bfhi(v5.x)) + (bfhi(v6.x) + bfhi(v7.x)));
        a2 += ((bflo(v0.y) + bflo(v1.y)) + (bflo(v2.y) + bflo(v3.y)))
            + ((bflo(v4.y) + bflo(v5.y)) + (bflo(v6.y) + bflo(v7.y)));
        a3 += ((bfhi(v0.y) + bfhi(v1.y)) + (bfhi(v2.y) + bfhi(v3.y)))
            + ((bfhi(v4.y) + bfhi(v5.y)) + (bfhi(v6.y) + bfhi(v7.y)));
        a4 += ((bflo(v0.z) + bflo(v1.z)) + (bflo(v2.z) + bflo(v3.z)))
            + ((bflo(v4.z) + bflo(v5.z)) + (bflo(v6.z) + bflo(v7.z)));
        a5 += ((bfhi(v0.z) + bfhi(v1.z)) + (bfhi(v2.z) + bfhi(v3.z)))
            + ((bfhi(v4.z) + bfhi(v5.z)) + (bfhi(v6.z) + bfhi(v7.z)));
        a6 += ((bflo(v0.w) + bflo(v1.w)) + (bflo(v2.w) + bflo(v3.w)))
            + ((bflo(v4.w) + bflo(v5.w)) + (bflo(v6.w) + bflo(v7.w)));
        a7 += ((bfhi(v0.w) + bfhi(v1.w)) + (bfhi(v2.w) + bfhi(v3.w)))
            + ((bfhi(v4.w) + bfhi(v5.w)) + (bfhi(v6.w) + bfhi(v7.w)));
    }
    for (; j + 4 <= end; j += 4) {
        const int s0 = edata[j + 0];
        const int s1 = edata[j + 1];
        const int s2 = edata[j + 2];
        const int s3 = edata[j + 3];
        const uint4 v0 = hq[(size_t)s0 * 8 + lane];
        const uint4 v1 = hq[(size_t)s1 * 8 + lane];
        const uint4 v2 = hq[(size_t)s2 * 8 + lane];
        const uint4 v3 = hq[(size_t)s3 * 8 + lane];
        a0 += (bflo(v0.x) + bflo(v1.x)) + (bflo(v2.x) + bflo(v3.x));
        a1 += (bfhi(v0.x) + bfhi(v1.x)) + (bfhi(v2.x) + bfhi(v3.x));
        a2 += (bflo(v0.y) + bflo(v1.y)) + (bflo(v2.y) + bflo(v3.y));
        a3 += (bfhi(v0.y) + bfhi(v1.y)) + (bfhi(v2.y) + bfhi(v3.y));
        a4 += (bflo(v0.z) + bflo(v1.z)) + (bflo(v2.z) + bflo(v3.z));
        a5 += (bfhi(v0.z) + bfhi(v1.z)) + (bfhi(v2.z) + bfhi(v3.z));
        a6 += (bflo(v0.w) + bflo(v1.w)) + (bflo(v2.w) + bflo(v3.w));
        a7 += (bfhi(v0.w) + bfhi(v1.w)) + (bfhi(v2.w) + bfhi(v3.w));
    }
    for (; j < end; ++j) {
        const int s = edata[j];
        const uint4 v = hq[(size_t)s * 8 + lane];
        a0 += bflo(v.x); a1 += bfhi(v.x);
        a2 += bflo(v.y); a3 += bfhi(v.y);
        a4 += bflo(v.z); a5 += bfhi(v.z);
        a6 += bflo(v.w); a7 += bfhi(v.w);
    }
    // self loop (hs already carries one dinv factor)
    {
        const uint4 v = hq[(size_t)node * 8 + lane];
        a0 += bflo(v.x); a1 += bfhi(v.x);
        a2 += bflo(v.y); a3 += bfhi(v.y);
        a4 += bflo(v.z); a5 += bfhi(v.z);
        a6 += bflo(v.w); a7 += bfhi(v.w);
    }

    const float di = dinv[node];
    const float4 b0 = *reinterpret_cast<const float4*>(&bias[lane * 8]);
    const float4 b1 = *reinterpret_cast<const float4*>(&bias[lane * 8 + 4]);
    float4 o0, o1;
    o0.x = a0 * di + b0.x;  o0.y = a1 * di + b0.y;
    o0.z = a2 * di + b0.z;  o0.w = a3 * di + b0.w;
    o1.x = a4 * di + b1.x;  o1.y = a5 * di + b1.y;
    o1.z = a6 * di + b1.z;  o1.w = a7 * di + b1.w;
    if (RELU) {
        o0.x = fmaxf(o0.x, 0.f); o0.y = fmaxf(o0.y, 0.f);
        o0.z = fmaxf(o0.z, 0.f); o0.w = fmaxf(o0.w, 0.f);
        o1.x = fmaxf(o1.x, 0.f); o1.y = fmaxf(o1.y, 0.f);
        o1.z = fmaxf(o1.z, 0.f); o1.w = fmaxf(o1.w, 0.f);
    }
    float4* op = (float4*)&out[(size_t)node * 64 + lane * 8];
    op[0] = o0;
    op[1] = o1;
}

extern "C" void kernel_launch(void* const* d_in, const int* in_sizes, int n_in,
                              void* d_out, int out_size, void* d_ws, size_t ws_size,
                              hipStream_t stream) {
    const float* x  = (const float*)d_in[0];
    const int*   ei = (const int*)d_in[1];    // [2, N_EDGES] int32
    const float* W1 = (const float*)d_in[2];
    const float* b1 = (const float*)d_in[3];
    const float* W2 = (const float*)d_in[4];
    const float* b2 = (const float*)d_in[5];
    float* out = (float*)d_out;

    // Workspace carve-up (all offsets keep 16B alignment for float4/uint4):
    //   histT[25088] | bucketstart[100] | brec[E] | rowstart[N+4] |
    //   edata ushort[E] | dinv[N] | hsb1[N*32 u32] | a1[N*64 f32] | hsb2[N*32]
    int*            histT       = (int*)d_ws;
    int*            bucketstart = histT + NB * NPB;             // 25088
    int*            brec        = bucketstart + (NB + 2);       // +100
    int*            rowstart    = brec + N_EDGES;
    unsigned short* edata       = (unsigned short*)(rowstart + (N_NODES + 4));
    float*          dinv        = (float*)(edata + N_EDGES);    // E even -> aligned
    uint32_t*       hsb1        = (uint32_t*)(dinv + N_NODES);  // bf16 [N][64]
    float*          a1          = (float*)(hsb1 + (size_t)N_NODES * 32);
    uint32_t*       hsb2        = (uint32_t*)(a1 + (size_t)N_NODES * 64);

    // --- CSR build (counting-sort partition) ---
    k_bhist<<<NPB, 256, 0, stream>>>(ei, histT);
    k_bscan<<<1, 256, 0, stream>>>(histT, bucketstart);
    k_part<<<NPB, 256, 0, stream>>>(ei, histT, brec);
    k_csr<<<NB, 256, 0, stream>>>(brec, bucketstart, rowstart, dinv, edata);

    const int GG = (N_NODES + 31) / 32;   // 1563 blocks per gather pass

    // --- layer 1 ---
    k_gemm3<IN_DIM><<<(N_NODES + 63) / 64, 256, 0, stream>>>(x, W1, dinv, hsb1, N_NODES);
    k_gather<true><<<GG, 256, 0, stream>>>(rowstart, edata, hsb1, dinv, b1, a1);

    // --- layer 2 ---
    k_gemm3<HID_DIM><<<(N_NODES + 63) / 64, 256, 0, stream>>>(a1, W2, dinv, hsb2, N_NODES);
    k_gather<false><<<GG, 256, 0, stream>>>(rowstart, edata, hsb2, dinv, b2, out);
}